// Round 3
// baseline (600.819 us; speedup 1.0000x reference)
//
#include <hip/hip_runtime.h>

// ---------------- node features: [velocity(3) | one_hot(9)] per node (12 f32 = 48 B) ----
__global__ void node_kernel(const float* __restrict__ w,
                            const float* __restrict__ p,
                            const int* __restrict__ nt,
                            float4* __restrict__ out, int n_nodes) {
    int i = blockIdx.x * blockDim.x + threadIdx.x;
    if (i >= n_nodes) return;
    size_t b = 3 * (size_t)i;
    float v0 = w[b + 0] - p[b + 0];
    float v1 = w[b + 1] - p[b + 1];
    float v2 = w[b + 2] - p[b + 2];
    int t = nt[i];
    float4 f0 = make_float4(v0, v1, v2, t == 0 ? 1.f : 0.f);
    float4 f1 = make_float4(t == 1 ? 1.f : 0.f, t == 2 ? 1.f : 0.f,
                            t == 3 ? 1.f : 0.f, t == 4 ? 1.f : 0.f);
    float4 f2 = make_float4(t == 5 ? 1.f : 0.f, t == 6 ? 1.f : 0.f,
                            t == 7 ? 1.f : 0.f, t == 8 ? 1.f : 0.f);
    float4* dst = out + 3 * (size_t)i;   // 48 B per row = 3 x float4
    dst[0] = f0;
    dst[1] = f1;
    dst[2] = f2;
}

// ---------------- edge features ----------------
// edge rows (8 f32 = 32 B = 2 x float4):
// [0,NC): a->b  [NC,2NC): b->c  [2NC,3NC): c->a ; [3NC,6NC): reversed (negated rels, same norms)
__device__ __forceinline__ void load3(const float* __restrict__ base, int n,
                                      float& x, float& y, float& z) {
    const float* q = base + 3 * (size_t)n;
    x = q[0]; y = q[1]; z = q[2];
}

__device__ __forceinline__ void emit(float4* __restrict__ ef, size_t e_fwd, size_t e_rev,
                                     float rwx, float rwy, float rwz,
                                     float rmx, float rmy, float rmz) {
    float nw = sqrtf(rwx * rwx + rwy * rwy + rwz * rwz);
    float nm = sqrtf(rmx * rmx + rmy * rmy + rmz * rmz);
    ef[2 * e_fwd + 0] = make_float4(rwx, rwy, rwz, nw);
    ef[2 * e_fwd + 1] = make_float4(rmx, rmy, rmz, nm);
    ef[2 * e_rev + 0] = make_float4(-rwx, -rwy, -rwz, nw);
    ef[2 * e_rev + 1] = make_float4(-rmx, -rmy, -rmz, nm);
}

__global__ void edge_kernel(const float* __restrict__ world,
                            const float* __restrict__ mesh,
                            const int* __restrict__ cells,
                            float4* __restrict__ ef, int n_cells) {
    int c = blockIdx.x * blockDim.x + threadIdx.x;
    if (c >= n_cells) return;
    size_t cb = 3 * (size_t)c;
    int ia = cells[cb + 0];
    int ib = cells[cb + 1];
    int ic = cells[cb + 2];

    float wax, way, waz, wbx, wby, wbz, wcx, wcy, wcz;
    load3(world, ia, wax, way, waz);
    load3(world, ib, wbx, wby, wbz);
    load3(world, ic, wcx, wcy, wcz);
    float max_, may_, maz_, mbx_, mby_, mbz_, mcx_, mcy_, mcz_;
    load3(mesh, ia, max_, may_, maz_);
    load3(mesh, ib, mbx_, mby_, mbz_);
    load3(mesh, ic, mcx_, mcy_, mcz_);

    size_t NC = (size_t)n_cells;
    size_t e = (size_t)c;
    // a->b at e        ; reverse (b->a) at e+3NC
    emit(ef, e,          e + 3 * NC,
         wax - wbx, way - wby, waz - wbz,
         max_ - mbx_, may_ - mby_, maz_ - mbz_);
    // b->c at e+NC     ; reverse (c->b) at e+4NC
    emit(ef, e + NC,     e + 4 * NC,
         wbx - wcx, wby - wcy, wbz - wcz,
         mbx_ - mcx_, mby_ - mcy_, mbz_ - mcz_);
    // c->a at e+2NC    ; reverse (a->c) at e+5NC
    emit(ef, e + 2 * NC, e + 5 * NC,
         wcx - wax, wcy - way, wcz - waz,
         mcx_ - max_, mcy_ - may_, mcz_ - maz_);
}

extern "C" void kernel_launch(void* const* d_in, const int* in_sizes, int n_in,
                              void* d_out, int out_size, void* d_ws, size_t ws_size,
                              hipStream_t stream) {
    const float* world = (const float*)d_in[0];
    const float* prev  = (const float*)d_in[1];
    const float* mesh  = (const float*)d_in[2];
    const int* ntype   = (const int*)d_in[3];
    const int* cells   = (const int*)d_in[4];
    int n_nodes = in_sizes[0] / 3;   // 1,000,000
    int n_cells = in_sizes[4] / 3;   // 2,000,000

    float* out = (float*)d_out;
    float4* nf = (float4*)out;                                   // node features: n_nodes x 12 f32
    float4* ef = (float4*)(out + (size_t)n_nodes * 12);          // edge features: 6*n_cells x 8 f32

    dim3 blk(256);
    dim3 g_node((n_nodes + 255) / 256);
    dim3 g_edge((n_cells + 255) / 256);
    node_kernel<<<g_node, blk, 0, stream>>>(world, prev, ntype, nf, n_nodes);
    edge_kernel<<<g_edge, blk, 0, stream>>>(world, mesh, cells, ef, n_cells);
}